// Round 12
// baseline (34.541 us; speedup 1.0000x reference)
//
#include <hip/hip_runtime.h>

// CondConv2d B=16,CIN=COUT=128,H=W=56,E=4,3x3,pad=1 fp32.
// (1) mix: fold routing into bf16 Wmix[b][cc][tap][co][ci_l] (conv linear in W).
// (2) conv: block=(b,h-pair): 128co x 128px x K=1152 GEMM on mfma_32x32x16_bf16.
//     512 thr / 8 waves (16 waves/CU at 2 blocks/CU). A: global_load_lds 4-buf
//     counted-vmcnt pipeline. B: x prefetched to REGISTERS 3 windows early
//     (T14), converted+written to a DOUBLE-BUFFERED xbuf at the cc boundary —
//     publish rides the next window barrier (no extra barriers, no x stall).
//     vmcnt bookkeeping: x-issue is exactly 16 VMEM/wave, pinned by
//     sched_barrier fences; windows after x-issue wait vmcnt(18)=16x+2A.

typedef float  f32x16 __attribute__((ext_vector_type(16)));
typedef short  s16x8  __attribute__((ext_vector_type(8)));
typedef unsigned short u16;

#define CIN   128
#define COUT  128
#define HH    56
#define WW    56
#define SP    (HH*WW)          // 3136
#define EW    147456           // per-expert W elems
#define BW_   147456           // per-sample Wmix elems: [cc4][tap9][co128][ci32]
#define XSTR  72               // xbuf row stride bytes (64 data + 8 pad)
#define XB    (4*66*XSTR)      // 19008 B per xbuf
#define AB    8192             // one A slab: 128 co x 32 ci bf16

static __device__ __forceinline__ u16 f2bf(float f) {
    unsigned u = __builtin_bit_cast(unsigned, f);
    return (u16)((u + 0x7FFFu + ((u >> 16) & 1u)) >> 16);
}

static __device__ __forceinline__ void gload16(const void* g, void* l) {
    __builtin_amdgcn_global_load_lds(
        (const __attribute__((address_space(1))) void*)g,
        (__attribute__((address_space(3))) void*)l, 16, 0, 0);
}

// ---------------------------------------------------------------------------
// mix: Wmix[b][cc][tap][co][ci_l] = sum_e r[b,e]*W[e][co][cc*32+ci_l][tap]
// ---------------------------------------------------------------------------
__global__ __launch_bounds__(256) void mix_kernel(const float* __restrict__ W,
                                                  const float* __restrict__ r,
                                                  u16* __restrict__ Wmix) {
    int o = blockIdx.x * 256 + threadIdx.x;      // [0, 147456)
    int ci_l = o & 31;
    int o2   = o >> 5;
    int co   = o2 & 127;
    int o3   = o2 >> 7;                          // [0,36)
    int tap  = o3 % 9;
    int cc   = o3 / 9;
    size_t src = ((size_t)co * CIN + cc*32 + ci_l) * 9 + tap;
    float w0 = W[src], w1 = W[src + EW], w2 = W[src + 2*EW], w3 = W[src + 3*EW];
    #pragma unroll
    for (int b = 0; b < 16; ++b) {
        float acc = r[b*4+0]*w0 + r[b*4+1]*w1 + r[b*4+2]*w2 + r[b*4+3]*w3;
        Wmix[(size_t)b * BW_ + o] = f2bf(acc);
    }
}

// ---------------------------------------------------------------------------
// conv kernel. LDS: xbuf[2][4 rows][66 cols][72B] + A[4][8KB] = 70784 B.
// ---------------------------------------------------------------------------
__global__ __launch_bounds__(512, 4) void conv_mfma(const float* __restrict__ x,
                                                    const u16* __restrict__ Wmix,
                                                    float* __restrict__ out) {
    __shared__ __align__(16) char ldsb[2*XB + 4*AB];

    const int bid = blockIdx.x;
    const int bs  = (bid & 7) * 56 + (bid >> 3);     // bijective XCD swizzle (448=8*56)
    const int b   = bs / 28;
    const int ph  = bs % 28;                         // rows {2ph, 2ph+1}
    const int t    = threadIdx.x;
    const int lane = t & 63;
    const int wid  = t >> 6;                         // 0..7
    const int wm   = (wid >> 2) & 1;                 // co half
    const int wn   = (wid >> 1) & 1;                 // output row within pair
    const int wp   = wid & 1;                        // px half
    const int l31  = lane & 31;
    const int khalf= lane >> 5;

    const u16*   WmixB = Wmix + (size_t)b * BW_;
    const float* xbB   = x + (size_t)b * CIN * SP;

    // A DMA: lane source row = t>>2, dest slot = t&3, src slot inverse-swizzled
    const int ssl = (t & 3) ^ ((t >> 3) & 3);

    // x staging slot precompute (2 slots per thread)
    bool  xok[2];
    const float* xsp[2];
    int   xdst[2];
    #pragma unroll
    for (int i = 0; i < 2; ++i) {
        int slot = i * 512 + t;                      // 0..1023
        int c    = 1 + (slot & 63);                  // col 1..64
        int row  = (slot >> 6) & 3;                  // 0..3
        int g    = slot >> 8;                        // ci group 0..3
        int rr   = 2*ph - 1 + row;                   // input row
        int w    = c - 1;
        xok[i]   = ((unsigned)rr < 56u) && (w < 56);
        xsp[i]   = xok[i] ? (xbB + (size_t)(g*8) * SP + rr*56 + w) : xbB;
        xdst[i]  = (row*66 + c)*XSTR + g*16;
    }
    float xr[2][8];

    auto issueX = [&](int cc) {                      // exactly 16 VMEM per wave
        #pragma unroll
        for (int i = 0; i < 2; ++i) {
            const float* p = xok[i] ? (xsp[i] + (size_t)cc*32*SP) : xbB;
            #pragma unroll
            for (int j = 0; j < 8; ++j) xr[i][j] = p[(size_t)j * SP];
        }
    };
    auto writeX = [&](int cc) {                      // convert + ds_write (dbuf)
        #pragma unroll
        for (int i = 0; i < 2; ++i) {
            s16x8 v;
            #pragma unroll
            for (int j = 0; j < 8; ++j)
                v[j] = xok[i] ? (short)f2bf(xr[i][j]) : (short)0;
            *(s16x8*)(ldsb + (cc & 1)*XB + xdst[i]) = v;
        }
    };

    auto stageA = [&](int it) {
        char* ldst = ldsb + 2*XB + (it & 3) * AB + wid * 1024;
        const u16* ga = WmixB + it * 4096 + (t >> 2) * 32 + ssl * 8;
        gload16(ga, ldst);
    };

    f32x16 acc[2];
    acc[0] = (f32x16)0.f;
    acc[1] = (f32x16)0.f;

    auto compute = [&](int it, int kh, int kw, int xbase) {
        const char* Ab = ldsb + 2*XB + (it & 3) * AB;
        #pragma unroll
        for (int ksub = 0; ksub < 2; ++ksub) {
            const int s = ksub * 2 + khalf;
            s16x8 af[2], bv;
            #pragma unroll
            for (int mf = 0; mf < 2; ++mf)
                af[mf] = *(const s16x8*)(Ab + (wm*64 + mf*32 + l31)*64
                                            + ((s ^ ((l31 >> 1) & 3)) * 16));
            const int c = wp*32 + l31 + kw;          // 0..65
            bv = *(const s16x8*)(ldsb + xbase + ((wn + kh)*66 + c)*XSTR + s*16);
            #pragma unroll
            for (int mf = 0; mf < 2; ++mf)
                acc[mf] = __builtin_amdgcn_mfma_f32_32x32x16_bf16(
                    af[mf], bv, acc[mf], 0, 0, 0);
        }
    };

    // --- prologue: zero halo cols of BOTH xbufs; x(0) to regs; A slabs 0,1 ---
    if (t < 64) {
        int bufi = (t >> 5) & 1, row = (t >> 3) & 3;
        int col = ((t >> 2) & 1) ? 65 : 0, sl = t & 3;
        *(s16x8*)(ldsb + bufi*XB + (row*66 + col)*XSTR + sl*16) = (s16x8)0;
    }
    issueX(0);
    __builtin_amdgcn_sched_barrier(0);
    stageA(0);
    stageA(1);
    __builtin_amdgcn_sched_barrier(0);
    asm volatile("s_waitcnt vmcnt(2)" ::: "memory");     // x16 landed, A0/A1 fly
    writeX(0);
    asm volatile("s_waitcnt lgkmcnt(0)" ::: "memory");
    __builtin_amdgcn_sched_barrier(0);
    // publish rides tap0's window barrier

    #pragma unroll
    for (int cc = 0; cc < 4; ++cc) {
        if (cc) {
            // boundary: x16 landed (2 A slabs younger, stay in flight)
            asm volatile("s_waitcnt vmcnt(2)" ::: "memory");
            writeX(cc);
            asm volatile("s_waitcnt lgkmcnt(0)" ::: "memory");
            __builtin_amdgcn_sched_barrier(0);
        }
        #pragma unroll
        for (int tap = 0; tap < 9; ++tap) {
            const int it = cc * 9 + tap;
            if (it + 2 < 36) stageA(it + 2);
            if (tap == 6 && cc < 3) {                // prefetch x for cc+1
                __builtin_amdgcn_sched_barrier(0);   // keep after stageA(it+2)
                issueX(cc + 1);
            }
            __builtin_amdgcn_sched_barrier(0);       // pin FIFO order
            if (cc < 3) {
                if (tap <= 6) asm volatile("s_waitcnt vmcnt(2)" ::: "memory");
                else          asm volatile("s_waitcnt vmcnt(18)" ::: "memory");
            } else {
                if      (tap <= 6) asm volatile("s_waitcnt vmcnt(2)" ::: "memory");
                else if (tap == 7) asm volatile("s_waitcnt vmcnt(1)" ::: "memory");
                else               asm volatile("s_waitcnt vmcnt(0)" ::: "memory");
            }
            __builtin_amdgcn_s_barrier();
            __builtin_amdgcn_sched_barrier(0);
            __builtin_amdgcn_s_setprio(1);
            compute(it, tap / 3, tap % 3, (cc & 1) * XB);
            __builtin_amdgcn_s_setprio(0);
        }
    }

    // store: D col(px)=l31, row(co) = (reg&3) + 8*(reg>>2) + 4*khalf
    const int w = wp * 32 + l31;
    if (w < 56) {
        const int hrow = 2 * ph + wn;
        #pragma unroll
        for (int mf = 0; mf < 2; ++mf) {
            #pragma unroll
            for (int rg = 0; rg < 16; ++rg) {
                int co = wm*64 + mf*32 + (rg & 3) + 8*(rg >> 2) + 4*khalf;
                out[(((size_t)b*COUT + co)*HH + hrow)*WW + w] = acc[mf][rg];
            }
        }
    }
}

extern "C" void kernel_launch(void* const* d_in, const int* in_sizes, int n_in,
                              void* d_out, int out_size, void* d_ws, size_t ws_size,
                              hipStream_t stream) {
    const float* x = (const float*)d_in[0];          // [16,128,56,56]
    const float* r = (const float*)d_in[1];          // [16,4]
    const float* W = (const float*)d_in[2];          // [4,128,128,3,3]
    float* outp = (float*)d_out;                     // [16,128,56,56]
    u16* Wmix = (u16*)d_ws;                          // 4.72 MB

    mix_kernel<<<576, 256, 0, stream>>>(W, r, Wmix);
    conv_mfma <<<448, 512, 0, stream>>>(x, Wmix, outp);
}